// Round 1
// baseline (436.919 us; speedup 1.0000x reference)
//
#include <hip/hip_runtime.h>
#include <math.h>

#define NATOMS  512
#define MROWS   64
#define BATCH   65536
#define BT      16          // batch columns per block
#define NSPARSE 5
#define DEPS    1e-6

// ---------------------------------------------------------------------------
// prep: gram = D^T D (f64 accumulate -> f32), plus D64 = (double)D
// grid: 512*512/256 = 1024 blocks x 256 threads
// ---------------------------------------------------------------------------
__global__ void ksvd_prep_kernel(const float* __restrict__ D,
                                 float* __restrict__ gram,
                                 double* __restrict__ D64) {
  const int idx = blockIdx.x * 256 + threadIdx.x;          // 0 .. 512*512-1
  if (idx < MROWS * NATOMS) D64[idx] = (double)D[idx];
  const int i = idx >> 9;
  const int j = idx & (NATOMS - 1);
  double acc = 0.0;
#pragma unroll 8
  for (int m = 0; m < MROWS; ++m)
    acc += (double)D[m * NATOMS + i] * (double)D[m * NATOMS + j];
  gram[idx] = (float)acc;
}

// ---------------------------------------------------------------------------
// unpivoted LU solve of (gram[active,active] + eps*I) sol = rhs, K <= 5.
// SPD with near-unit diagonal -> pivoting unnecessary. Fully static indexing.
// ---------------------------------------------------------------------------
template <int K>
__device__ __forceinline__ void solve_spd(const float* __restrict__ gram,
                                          const int* idxs, const double* rhs,
                                          double* sol) {
  double A[K][K], b[K];
#pragma unroll
  for (int i = 0; i < K; ++i) {
    b[i] = rhs[i];
#pragma unroll
    for (int j = 0; j < K; ++j)
      A[i][j] = (double)gram[idxs[i] * NATOMS + idxs[j]];
    A[i][i] += DEPS;
  }
#pragma unroll
  for (int p = 0; p < K; ++p) {
    double inv = 1.0 / A[p][p];
#pragma unroll
    for (int r = p + 1; r < K; ++r) {
      double f = A[r][p] * inv;
#pragma unroll
      for (int c = p + 1; c < K; ++c)
        A[r][c] -= f * A[p][c];
      b[r] -= f * b[p];
    }
  }
#pragma unroll
  for (int i = K - 1; i >= 0; --i) {
    double s = b[i];
#pragma unroll
    for (int j = i + 1; j < K; ++j)
      s -= A[i][j] * sol[j];
    sol[i] = s / A[i][i];
  }
}

// ---------------------------------------------------------------------------
// main: per block = 16 batch columns. Phase 1: dtx = D^T x (f64). Phase 2:
// OMP iterations, wave-per-column. Epilogue: coalesced full-tile C write.
// ---------------------------------------------------------------------------
__global__ __launch_bounds__(256) void ksvd_omp_kernel(
    const float* __restrict__ X, const double* __restrict__ D64,
    const float* __restrict__ gram, float* __restrict__ out) {
  __shared__ float dtx[NATOMS][BT + 1];      // [512][17]: pad -> conflict-free
  __shared__ int   sel_idx[BT][NSPARSE];
  __shared__ float sel_val[BT][NSPARSE];

  const int t    = threadIdx.x;
  const int lane = t & 63;
  const int wave = t >> 6;                   // 4 waves
  const int b0   = blockIdx.x * BT;
  const int cw   = wave * 4;                 // this wave's first column

  // ---------------- phase 1: dtx for 4 columns; lane owns n = lane + 64*jn
  double acc[8][4];
#pragma unroll
  for (int jn = 0; jn < 8; ++jn)
#pragma unroll
    for (int q = 0; q < 4; ++q) acc[jn][q] = 0.0;

#pragma unroll 2
  for (int m = 0; m < MROWS; ++m) {
    const float4 xv =
        *reinterpret_cast<const float4*>(&X[(size_t)m * BATCH + b0 + cw]);
    const double x0 = (double)xv.x, x1 = (double)xv.y;
    const double x2 = (double)xv.z, x3 = (double)xv.w;
#pragma unroll
    for (int jn = 0; jn < 8; ++jn) {
      const double dv = D64[m * NATOMS + lane + 64 * jn];
      acc[jn][0] += dv * x0;
      acc[jn][1] += dv * x1;
      acc[jn][2] += dv * x2;
      acc[jn][3] += dv * x3;
    }
  }
#pragma unroll
  for (int jn = 0; jn < 8; ++jn)
#pragma unroll
    for (int q = 0; q < 4; ++q)
      dtx[lane + 64 * jn][cw + q] = (float)acc[jn][q];
  // lane reads back only its own writes -> no barrier needed before phase 2

  // ---------------- phase 2: OMP, wave processes its 4 columns sequentially
  for (int cc = 0; cc < 4; ++cc) {
    const int c = cw + cc;
    float dtxr[8];
#pragma unroll
    for (int j = 0; j < 8; ++j) dtxr[j] = dtx[lane + 64 * j][c];

    unsigned mask8 = 0;                       // my 8 atoms' selected bits
    int    idxs[NSPARSE];
    double rhs[NSPARSE];
    double sol[NSPARSE];
    float  gcol[NSPARSE][8];                  // cached gram columns

#pragma unroll
    for (int k = 0; k < NSPARSE; ++k) {
      // corr = dtx - sum_s sol[s]*gram[:,idx_s]; local masked abs-argmax
      double bv = -1.0;
      int    bn = 1 << 20;
#pragma unroll
      for (int j = 0; j < 8; ++j) {
        double cv = (double)dtxr[j];
#pragma unroll
        for (int s = 0; s < k; ++s) cv -= sol[s] * (double)gcol[s][j];
        const double av = fabs(cv);
        const bool masked = (mask8 >> j) & 1u;
        const int n = lane + 64 * j;            // ascending j => ascending n
        if (!masked && av > bv) { bv = av; bn = n; }
      }
      // wave argmax reduce; ties -> smaller n (matches jnp.argmax first-max)
#pragma unroll
      for (int off = 32; off > 0; off >>= 1) {
        const double ov = __shfl_xor(bv, off);
        const int    on = __shfl_xor(bn, off);
        if (ov > bv || (ov == bv && on < bn)) { bv = ov; bn = on; }
      }
      const int idx = bn;                       // uniform across the wave
      idxs[k] = idx;
      if ((idx & 63) == lane) mask8 |= 1u << (idx >> 6);

      // rhs[k] = dtx[idx]  (owner lane = idx&63, reg slot = idx>>6, uniform)
      {
        const int ju = idx >> 6;
        float dv = dtxr[0];
#pragma unroll
        for (int j = 1; j < 8; ++j)
          if (j == ju) dv = dtxr[j];
        rhs[k] = (double)__shfl(dv, idx & 63);
      }
      // cache the new gram column (coalesced, L2-resident)
#pragma unroll
      for (int j = 0; j < 8; ++j)
        gcol[k][j] = gram[idx * NATOMS + lane + 64 * j];

      // solve (k+1)x(k+1); k is a compile-time constant after unroll
      if      (k == 0) solve_spd<1>(gram, idxs, rhs, sol);
      else if (k == 1) solve_spd<2>(gram, idxs, rhs, sol);
      else if (k == 2) solve_spd<3>(gram, idxs, rhs, sol);
      else if (k == 3) solve_spd<4>(gram, idxs, rhs, sol);
      else             solve_spd<5>(gram, idxs, rhs, sol);
    }

    if (lane == 0) {
#pragma unroll
      for (int s = 0; s < NSPARSE; ++s) {
        sel_idx[c][s] = idxs[s];
        sel_val[c][s] = (float)sol[s];
      }
    }
  }

  __syncthreads();

  // ---------------- epilogue: write the full 512x16 tile (mostly zeros)
#pragma unroll
  for (int step = 0; step < 8; ++step) {
    const int n  = (t >> 2) + 64 * step;
    const int c4 = (t & 3) * 4;
    float v[4];
#pragma unroll
    for (int q = 0; q < 4; ++q) {
      const int c = c4 + q;
      float val = 0.0f;
#pragma unroll
      for (int s = 0; s < NSPARSE; ++s)
        if (sel_idx[c][s] == n) val = sel_val[c][s];
      v[q] = val;
    }
    float4 vv;
    vv.x = v[0]; vv.y = v[1]; vv.z = v[2]; vv.w = v[3];
    *reinterpret_cast<float4*>(&out[(size_t)n * BATCH + b0 + c4]) = vv;
  }
}

// ---------------------------------------------------------------------------
extern "C" void kernel_launch(void* const* d_in, const int* in_sizes, int n_in,
                              void* d_out, int out_size, void* d_ws,
                              size_t ws_size, hipStream_t stream) {
  (void)in_sizes; (void)n_in; (void)out_size; (void)ws_size;
  const float* X = (const float*)d_in[0];   // (64, 65536)
  const float* D = (const float*)d_in[1];   // (64, 512)
  float* out = (float*)d_out;               // (512, 65536)

  float*  gram = (float*)d_ws;                                  // 1 MB
  double* D64  = (double*)((char*)d_ws + (1 << 20));            // 256 KB

  ksvd_prep_kernel<<<(NATOMS * NATOMS) / 256, 256, 0, stream>>>(D, gram, D64);
  ksvd_omp_kernel<<<BATCH / BT, 256, 0, stream>>>(X, D64, gram, out);
}

// Round 2
// 298.163 us; speedup vs baseline: 1.4654x; 1.4654x over previous
//
#include <hip/hip_runtime.h>
#include <math.h>

#define NATOMS  512
#define MROWS   64
#define BATCH   65536
#define BT      4           // batch columns per block (1 per wave)
#define NSPARSE 5
#define DEPS    1e-6

// ---------------------------------------------------------------------------
// prep: gram = D^T D (f64 accumulate -> f32). 1024 blocks x 256.
// i is block-uniform (scalar load), j coalesced.
// ---------------------------------------------------------------------------
__global__ void ksvd_prep(const float* __restrict__ D,
                          float* __restrict__ gram) {
  const int idx = blockIdx.x * 256 + threadIdx.x;     // 0 .. 512*512-1
  const int i = idx >> 9;
  const int j = idx & (NATOMS - 1);
  double acc = 0.0;
#pragma unroll 8
  for (int m = 0; m < MROWS; ++m)
    acc += (double)D[m * NATOMS + i] * (double)D[m * NATOMS + j];
  gram[idx] = (float)acc;
}

// ---------------------------------------------------------------------------
// main: block = 256 threads = 4 waves = 4 batch columns (one column / wave).
// Phase 1: dtx = D^T x, f64 accum, block-shared X, f32 D loads (cvt exact).
// Phase 2: OMP with incremental Cholesky fully in registers; the active
// Gram matrix rows are extracted from cached gram columns via __shfl
// (A[k][j] = gcol_j[idx_k]) -- zero global loads in the solve.
// Epilogue: scatter 5 nonzeros per column (out pre-zeroed by memset).
// ---------------------------------------------------------------------------
__global__ __launch_bounds__(256, 4) void ksvd_main(
    const float* __restrict__ X, const float* __restrict__ D,
    const float* __restrict__ gram, float* __restrict__ out) {
  __shared__ double xs64[MROWS][BT];            // 2 KB
  __shared__ float  dtxT[BT][NATOMS + 8];       // 4 x 520 floats = 8.3 KB

  const int t    = threadIdx.x;
  const int lane = t & 63;
  const int wave = t >> 6;                      // 0..3
  const int b0   = blockIdx.x * BT;

  // ---- stage X tile (64 m x 4 c) as f64, converted once
  {
    const int m = t >> 2, c = t & 3;
    xs64[m][c] = (double)X[(size_t)m * BATCH + b0 + c];
  }
  __syncthreads();

  // ---- phase 1: lane owns atoms a0 = 128*wave + lane and a0+64
  double acc[2][BT];
#pragma unroll
  for (int q = 0; q < 2; ++q)
#pragma unroll
    for (int c = 0; c < BT; ++c) acc[q][c] = 0.0;

  const int a0 = wave * 128 + lane;
#pragma unroll 4
  for (int m = 0; m < MROWS; ++m) {
    const double d0 = (double)D[m * NATOMS + a0];
    const double d1 = (double)D[m * NATOMS + a0 + 64];
    const double x0 = xs64[m][0], x1 = xs64[m][1];
    const double x2 = xs64[m][2], x3 = xs64[m][3];
    acc[0][0] += d0 * x0; acc[0][1] += d0 * x1;
    acc[0][2] += d0 * x2; acc[0][3] += d0 * x3;
    acc[1][0] += d1 * x0; acc[1][1] += d1 * x1;
    acc[1][2] += d1 * x2; acc[1][3] += d1 * x3;
  }
#pragma unroll
  for (int c = 0; c < BT; ++c) {
    dtxT[c][a0]      = (float)acc[0][c];
    dtxT[c][a0 + 64] = (float)acc[1][c];
  }
  __syncthreads();

  // ---- phase 2: this wave's column; lane owns 8 consecutive atoms 8l..8l+7
  const int cglob = b0 + wave;
  float dtxr[8];
  {
    const float4 f0 = *reinterpret_cast<const float4*>(&dtxT[wave][8 * lane]);
    const float4 f1 = *reinterpret_cast<const float4*>(&dtxT[wave][8 * lane + 4]);
    dtxr[0] = f0.x; dtxr[1] = f0.y; dtxr[2] = f0.z; dtxr[3] = f0.w;
    dtxr[4] = f1.x; dtxr[5] = f1.y; dtxr[6] = f1.z; dtxr[7] = f1.w;
  }

  unsigned mask8 = 0;                       // selected bits among my 8 atoms
  int    idxs[NSPARSE];
  float  rhsf[NSPARSE];
  float  gc[NSPARSE - 1][8];                // cached gram columns (f32)
  double L[NSPARSE][NSPARSE];               // lower-tri Cholesky (static idx)
  double inv_d[NSPARSE];
  double sol[NSPARSE];

#pragma unroll
  for (int k = 0; k < NSPARSE; ++k) {
    // corr = dtx - sum_s sol[s]*gcol_s; masked abs-argmax (local 8 atoms)
    double bv = -1.0;
    int    bn = 0;
#pragma unroll
    for (int jj = 0; jj < 8; ++jj) {
      double cv = (double)dtxr[jj];
#pragma unroll
      for (int s = 0; s < k; ++s) cv -= sol[s] * (double)gc[s][jj];
      double av = fabs(cv);
      if ((mask8 >> jj) & 1u) av = -1.0;
      if (av > bv) { bv = av; bn = 8 * lane + jj; }   // ascending jj: first-max
    }
    // wave butterfly; ties -> smaller atom index (jnp.argmax first-max)
#pragma unroll
    for (int off = 1; off < 64; off <<= 1) {
      const double ov = __shfl_xor(bv, off);
      const int    on = __shfl_xor(bn, off);
      if (ov > bv || (ov == bv && on < bn)) { bv = ov; bn = on; }
    }
    const int idx = bn;                     // uniform
    idxs[k] = idx;
    const int ol = idx >> 3, sl = idx & 7;  // owner lane / slot
    if (ol == lane) mask8 |= 1u << sl;

    // issue the gram-column load early (latency overlaps the shfl/chol work)
    float4 g0, g1;
    if (k < NSPARSE - 1) {
      g0 = *reinterpret_cast<const float4*>(&gram[(size_t)idx * NATOMS + 8 * lane]);
      g1 = *reinterpret_cast<const float4*>(&gram[(size_t)idx * NATOMS + 8 * lane + 4]);
    }

    // rhs[k] = dtx[idx]
    {
      float dsel = dtxr[0];
#pragma unroll
      for (int j = 1; j < 8; ++j)
        if (sl == j) dsel = dtxr[j];
      rhsf[k] = __shfl(dsel, ol);
    }

    // A row k from previously cached gram columns: A[k][j] = gc[j][atom idx]
    double arow[NSPARSE];
#pragma unroll
    for (int j = 0; j < k; ++j) {
      float gsel = gc[j][0];
#pragma unroll
      for (int q = 1; q < 8; ++q)
        if (sl == q) gsel = gc[j][q];
      arow[j] = (double)__shfl(gsel, ol);
    }

    // diagonal gram[idx][idx]
    float gdiag;
    if (k < NSPARSE - 1) {
      gc[k][0] = g0.x; gc[k][1] = g0.y; gc[k][2] = g0.z; gc[k][3] = g0.w;
      gc[k][4] = g1.x; gc[k][5] = g1.y; gc[k][6] = g1.z; gc[k][7] = g1.w;
      float gs = gc[k][0];
#pragma unroll
      for (int q = 1; q < 8; ++q)
        if (sl == q) gs = gc[k][q];
      gdiag = __shfl(gs, ol);
    } else {
      gdiag = gram[(size_t)idx * NATOMS + idx];   // uniform scalar load
    }

    // incremental Cholesky row k of (G_active + eps*I)
    double ss = (double)gdiag + DEPS;
#pragma unroll
    for (int j = 0; j < k; ++j) {
      double w = arow[j];
#pragma unroll
      for (int tt = 0; tt < j; ++tt) w -= L[k][tt] * L[j][tt];
      w *= inv_d[j];
      L[k][j] = w;
      ss -= w * w;
    }
    L[k][k]  = sqrt(ss);
    inv_d[k] = 1.0 / L[k][k];

    // solve (L L^T) sol = rhs, in place (fwd then bwd)
#pragma unroll
    for (int i = 0; i <= k; ++i) {
      double s2 = (double)rhsf[i];
#pragma unroll
      for (int j = 0; j < i; ++j) s2 -= L[i][j] * sol[j];
      sol[i] = s2 * inv_d[i];
    }
#pragma unroll
    for (int i = k; i >= 0; --i) {
      double s2 = sol[i];
#pragma unroll
      for (int j = i + 1; j <= k; ++j) s2 -= L[j][i] * sol[j];
      sol[i] = s2 * inv_d[i];
    }
  }

  // ---- epilogue: scatter the 5 coefficients (out pre-zeroed)
  if (lane == 0) {
#pragma unroll
    for (int s = 0; s < NSPARSE; ++s)
      out[(size_t)idxs[s] * BATCH + cglob] = (float)sol[s];
  }
}

// ---------------------------------------------------------------------------
extern "C" void kernel_launch(void* const* d_in, const int* in_sizes, int n_in,
                              void* d_out, int out_size, void* d_ws,
                              size_t ws_size, hipStream_t stream) {
  (void)in_sizes; (void)n_in; (void)out_size; (void)ws_size;
  const float* X = (const float*)d_in[0];   // (64, 65536)
  const float* D = (const float*)d_in[1];   // (64, 512)
  float* out = (float*)d_out;               // (512, 65536)
  float* gram = (float*)d_ws;               // 1 MB scratch

  ksvd_prep<<<(NATOMS * NATOMS) / 256, 256, 0, stream>>>(D, gram);
  hipMemsetAsync(out, 0, (size_t)NATOMS * BATCH * sizeof(float), stream);
  ksvd_main<<<BATCH / BT, 256, 0, stream>>>(X, D, gram, out);
}

// Round 3
// 229.622 us; speedup vs baseline: 1.9028x; 1.2985x over previous
//
#include <hip/hip_runtime.h>
#include <math.h>

#define NATOMS  512
#define MROWS   64
#define BATCH   65536
#define BT      4           // batch columns per block (1 per wave)
#define NSPARSE 5
#define DEPS    1e-6

// ---------------------------------------------------------------------------
// prep: gram = D^T D (f64 accumulate -> f32) + D64 = (double)D.
// 1024 blocks x 256 threads. i block-uniform, j coalesced.
// ---------------------------------------------------------------------------
__global__ void ksvd_prep(const float* __restrict__ D,
                          float* __restrict__ gram,
                          double* __restrict__ D64) {
  const int idx = blockIdx.x * 256 + threadIdx.x;     // 0 .. 512*512-1
  if (idx < MROWS * NATOMS) D64[idx] = (double)D[idx];
  const int i = idx >> 9;
  const int j = idx & (NATOMS - 1);
  double acc = 0.0;
#pragma unroll 8
  for (int m = 0; m < MROWS; ++m)
    acc += (double)D[m * NATOMS + i] * (double)D[m * NATOMS + j];
  gram[idx] = (float)acc;
}

// ---------------------------------------------------------------------------
// main: block = 4 waves = 4 batch columns (one per wave).
// Phase 1: dtx = D^T x, f64 FMA from D64 (double2 loads) and LDS-staged x.
// Phase 2: OMP; argmax via packed-key v_max_f64 butterfly (index in low
// mantissa bits, ties -> smaller atom = jnp first-max); no explicit mask
// (selected atoms have corr = eps*sol ~ 1e-5, can never win); rhs via one
// uniform LDS read; Gram row entries via uniform (scalar) loads; incremental
// Cholesky in registers. Epilogue: 5-element scatter (out pre-zeroed).
// ---------------------------------------------------------------------------
__global__ __launch_bounds__(256, 4) void ksvd_main(
    const float* __restrict__ X, const double* __restrict__ D64,
    const float* __restrict__ gram, float* __restrict__ out) {
  __shared__ __align__(16) double xs64[MROWS][BT];       // 2 KB
  __shared__ __align__(16) float  dtxT[BT][NATOMS + 8];  // 8.3 KB

  const int t    = threadIdx.x;
  const int lane = t & 63;
  const int wave = t >> 6;                      // 0..3
  const int b0   = blockIdx.x * BT;

  // ---- stage X tile (64 m x 4 c) as f64, converted once
  {
    const int m = t >> 2, c = t & 3;
    xs64[m][c] = (double)X[(size_t)m * BATCH + b0 + c];
  }
  __syncthreads();

  // ---- phase 1: lane owns atoms a0 = 128*wave + 2*lane and a0+1
  double acc[2][BT];
#pragma unroll
  for (int q = 0; q < 2; ++q)
#pragma unroll
    for (int c = 0; c < BT; ++c) acc[q][c] = 0.0;

  const int a0 = wave * 128 + 2 * lane;
#pragma unroll 8
  for (int m = 0; m < MROWS; ++m) {
    const double2 dv  = *reinterpret_cast<const double2*>(&D64[m * NATOMS + a0]);
    const double2 x01 = *reinterpret_cast<const double2*>(&xs64[m][0]);
    const double2 x23 = *reinterpret_cast<const double2*>(&xs64[m][2]);
    acc[0][0] += dv.x * x01.x; acc[0][1] += dv.x * x01.y;
    acc[0][2] += dv.x * x23.x; acc[0][3] += dv.x * x23.y;
    acc[1][0] += dv.y * x01.x; acc[1][1] += dv.y * x01.y;
    acc[1][2] += dv.y * x23.x; acc[1][3] += dv.y * x23.y;
  }
#pragma unroll
  for (int c = 0; c < BT; ++c) {
    dtxT[c][a0]     = (float)acc[0][c];
    dtxT[c][a0 + 1] = (float)acc[1][c];
  }
  __syncthreads();

  // ---- phase 2: this wave's column; lane owns 8 consecutive atoms 8l..8l+7
  const int cglob = b0 + wave;
  float dtxr[8];
  {
    const float4 f0 = *reinterpret_cast<const float4*>(&dtxT[wave][8 * lane]);
    const float4 f1 = *reinterpret_cast<const float4*>(&dtxT[wave][8 * lane + 4]);
    dtxr[0] = f0.x; dtxr[1] = f0.y; dtxr[2] = f0.z; dtxr[3] = f0.w;
    dtxr[4] = f1.x; dtxr[5] = f1.y; dtxr[6] = f1.z; dtxr[7] = f1.w;
  }

  int    idxs[NSPARSE];
  float  rhsf[NSPARSE];
  float  gc[NSPARSE - 1][8];                // cached gram columns (f32)
  double L[NSPARSE][NSPARSE];               // lower-tri Cholesky (static idx)
  double inv_d[NSPARSE];
  double sol[NSPARSE];

#pragma unroll
  for (int k = 0; k < NSPARSE; ++k) {
    // ---- corr = dtx - sum_s sol[s]*gc_s; packed-key abs-argmax
    double kmax = 0.0;
#pragma unroll
    for (int jj = 0; jj < 8; ++jj) {
      double cv = (double)dtxr[jj];
#pragma unroll
      for (int s = 0; s < k; ++s) cv -= sol[s] * (double)gc[s][jj];
      unsigned long long kb = __builtin_bit_cast(unsigned long long, fabs(cv));
      kb = (kb & ~0xFFFFull) | (unsigned long long)(511 - (8 * lane + jj));
      kmax = fmax(kmax, __builtin_bit_cast(double, kb));
    }
#pragma unroll
    for (int off = 1; off < 64; off <<= 1)
      kmax = fmax(kmax, __shfl_xor(kmax, off));
    int idx = 511 - (int)(__builtin_bit_cast(unsigned long long, kmax) & 0xFFFFull);
    idx = __builtin_amdgcn_readfirstlane(idx);
    idxs[k] = idx;

    // ---- gram column for future corr updates (vector, L2-resident)
    if (k < NSPARSE - 1) {
      const float4 g0 = *reinterpret_cast<const float4*>(
          &gram[(size_t)idx * NATOMS + 8 * lane]);
      const float4 g1 = *reinterpret_cast<const float4*>(
          &gram[(size_t)idx * NATOMS + 8 * lane + 4]);
      gc[k][0] = g0.x; gc[k][1] = g0.y; gc[k][2] = g0.z; gc[k][3] = g0.w;
      gc[k][4] = g1.x; gc[k][5] = g1.y; gc[k][6] = g1.z; gc[k][7] = g1.w;
    }

    // ---- rhs: one uniform LDS read (broadcast)
    rhsf[k] = dtxT[wave][idx];

    // ---- Gram row k entries: uniform addresses -> scalar loads
    float arowf[NSPARSE];
#pragma unroll
    for (int j = 0; j < k; ++j)
      arowf[j] = gram[(size_t)idx * NATOMS + idxs[j]];
    const float gdiag = gram[(size_t)idx * NATOMS + idx];

    // ---- incremental Cholesky row k of (G_active + eps*I)
    double ss = (double)gdiag + DEPS;
#pragma unroll
    for (int j = 0; j < k; ++j) {
      double w = (double)arowf[j];
#pragma unroll
      for (int tt = 0; tt < j; ++tt) w -= L[k][tt] * L[j][tt];
      w *= inv_d[j];
      L[k][j] = w;
      ss -= w * w;
    }
    L[k][k]  = sqrt(ss);
    inv_d[k] = 1.0 / L[k][k];

    // ---- solve (L L^T) sol = rhs (fwd then bwd)
#pragma unroll
    for (int i = 0; i <= k; ++i) {
      double s2 = (double)rhsf[i];
#pragma unroll
      for (int j = 0; j < i; ++j) s2 -= L[i][j] * sol[j];
      sol[i] = s2 * inv_d[i];
    }
#pragma unroll
    for (int i = k; i >= 0; --i) {
      double s2 = sol[i];
#pragma unroll
      for (int j = i + 1; j <= k; ++j) s2 -= L[j][i] * sol[j];
      sol[i] = s2 * inv_d[i];
    }
  }

  // ---- epilogue: scatter the 5 coefficients (out pre-zeroed)
  if (lane == 0) {
#pragma unroll
    for (int s = 0; s < NSPARSE; ++s)
      out[(size_t)idxs[s] * BATCH + cglob] = (float)sol[s];
  }
}

// ---------------------------------------------------------------------------
extern "C" void kernel_launch(void* const* d_in, const int* in_sizes, int n_in,
                              void* d_out, int out_size, void* d_ws,
                              size_t ws_size, hipStream_t stream) {
  (void)in_sizes; (void)n_in; (void)out_size; (void)ws_size;
  const float* X = (const float*)d_in[0];   // (64, 65536)
  const float* D = (const float*)d_in[1];   // (64, 512)
  float* out = (float*)d_out;               // (512, 65536)

  float*  gram = (float*)d_ws;                              // 1 MB
  double* D64  = (double*)((char*)d_ws + (1 << 20));        // 256 KB

  ksvd_prep<<<(NATOMS * NATOMS) / 256, 256, 0, stream>>>(D, gram, D64);
  hipMemsetAsync(out, 0, (size_t)NATOMS * BATCH * sizeof(float), stream);
  ksvd_main<<<BATCH / BT, 256, 0, stream>>>(X, D64, gram, out);
}

// Round 4
// 185.989 us; speedup vs baseline: 2.3492x; 1.2346x over previous
//
#include <hip/hip_runtime.h>
#include <math.h>

#define NATOMS  512
#define MROWS   64
#define BATCH   65536
#define BT      4           // batch columns per block (1 per wave)
#define NSPARSE 5
#define DEPS    1e-6

// ---------------------------------------------------------------------------
// prep: gram = D^T D (f64 accumulate -> f32). 1024 blocks x 256 threads.
// ---------------------------------------------------------------------------
__global__ void ksvd_prep(const float* __restrict__ D,
                          float* __restrict__ gram) {
  const int idx = blockIdx.x * 256 + threadIdx.x;     // 0 .. 512*512-1
  const int i = idx >> 9;
  const int j = idx & (NATOMS - 1);
  double acc = 0.0;
#pragma unroll 8
  for (int m = 0; m < MROWS; ++m)
    acc += (double)D[m * NATOMS + i] * (double)D[m * NATOMS + j];
  gram[idx] = (float)acc;
}

// ---------------------------------------------------------------------------
// main: block = 4 waves = 4 batch columns (one per wave).
// Phase 1: dtx = D^T x in f32 FMA (reference computes dt_x in f32; two
//   partial accumulators halve the sequential-sum error).
// Phase 2: OMP. corr evaluated in f64 from the f32 dtx/gram/sol chain;
//   argmax key rounded to f32 and reduced with a v_max_f32 butterfly +
//   ballot owner-resolve -> identical compare semantics to jnp.argmax on
//   f32 (first-max ties: lowest lane & lowest slot win). Incremental
//   Cholesky with rsqrt (no f64 div/sqrt sequences) and incremental
//   forward substitution. Epilogue: 5-element scatter (out pre-zeroed).
// ---------------------------------------------------------------------------
__global__ __launch_bounds__(256, 4) void ksvd_main(
    const float* __restrict__ X, const float* __restrict__ D,
    const float* __restrict__ gram, float* __restrict__ out) {
  __shared__ __align__(16) float xs[MROWS][BT];          // 1 KB
  __shared__ __align__(16) float dtxT[BT][NATOMS + 8];   // 8.3 KB

  const int t    = threadIdx.x;
  const int lane = t & 63;
  const int wave = t >> 6;                      // 0..3
  const int b0   = blockIdx.x * BT;

  // ---- stage X tile (64 m x 4 c)
  {
    const int m = t >> 2, c = t & 3;
    xs[m][c] = X[(size_t)m * BATCH + b0 + c];
  }
  __syncthreads();

  // ---- phase 1: lane owns atoms a0 = 128*wave + 2*lane and a0+1 (f32 FMA)
  const int a0 = wave * 128 + 2 * lane;
  float accA[2][BT], accB[2][BT];
#pragma unroll
  for (int q = 0; q < 2; ++q)
#pragma unroll
    for (int c = 0; c < BT; ++c) { accA[q][c] = 0.0f; accB[q][c] = 0.0f; }

#pragma unroll 4
  for (int m = 0; m < MROWS; m += 2) {
    const float2 d0 = *reinterpret_cast<const float2*>(&D[m * NATOMS + a0]);
    const float2 d1 = *reinterpret_cast<const float2*>(&D[(m + 1) * NATOMS + a0]);
    const float4 xa = *reinterpret_cast<const float4*>(&xs[m][0]);
    const float4 xb = *reinterpret_cast<const float4*>(&xs[m + 1][0]);
    accA[0][0] += d0.x * xa.x; accA[0][1] += d0.x * xa.y;
    accA[0][2] += d0.x * xa.z; accA[0][3] += d0.x * xa.w;
    accA[1][0] += d0.y * xa.x; accA[1][1] += d0.y * xa.y;
    accA[1][2] += d0.y * xa.z; accA[1][3] += d0.y * xa.w;
    accB[0][0] += d1.x * xb.x; accB[0][1] += d1.x * xb.y;
    accB[0][2] += d1.x * xb.z; accB[0][3] += d1.x * xb.w;
    accB[1][0] += d1.y * xb.x; accB[1][1] += d1.y * xb.y;
    accB[1][2] += d1.y * xb.z; accB[1][3] += d1.y * xb.w;
  }
#pragma unroll
  for (int c = 0; c < BT; ++c) {
    dtxT[c][a0]     = accA[0][c] + accB[0][c];
    dtxT[c][a0 + 1] = accA[1][c] + accB[1][c];
  }
  __syncthreads();

  // ---- phase 2: this wave's column; lane owns 8 consecutive atoms 8l..8l+7
  const int cglob = b0 + wave;
  double dtxd[8];
  {
    const float4 f0 = *reinterpret_cast<const float4*>(&dtxT[wave][8 * lane]);
    const float4 f1 = *reinterpret_cast<const float4*>(&dtxT[wave][8 * lane + 4]);
    dtxd[0] = (double)f0.x; dtxd[1] = (double)f0.y;
    dtxd[2] = (double)f0.z; dtxd[3] = (double)f0.w;
    dtxd[4] = (double)f1.x; dtxd[5] = (double)f1.y;
    dtxd[6] = (double)f1.z; dtxd[7] = (double)f1.w;
  }

  int    idxs[NSPARSE];
  float  rhsf[NSPARSE];
  float  gc[NSPARSE - 1][8];                // cached gram columns (f32)
  double L[NSPARSE][NSPARSE];               // lower-tri Cholesky (static idx)
  double inv_d[NSPARSE];
  double y[NSPARSE];                        // forward-substitution state
  double sol[NSPARSE];

#pragma unroll
  for (int k = 0; k < NSPARSE; ++k) {
    // ---- corr = dtx - sum_s sol[s]*gc_s (f64 eval of the f32-input chain);
    //      key in f32 => compare semantics == reference's f32 argmax
    float bv = -1.0f;
    int   bn = 0;
#pragma unroll
    for (int jj = 0; jj < 8; ++jj) {
      double cv = dtxd[jj];
#pragma unroll
      for (int s = 0; s < k; ++s) cv -= sol[s] * (double)gc[s][jj];
      const float av = fabsf((float)cv);
      if (av > bv) { bv = av; bn = 8 * lane + jj; }   // strict > : first-max
    }
    float wmax = bv;
#pragma unroll
    for (int off = 1; off < 64; off <<= 1)
      wmax = fmaxf(wmax, __shfl_xor(wmax, off));
    const unsigned long long own = __ballot(bv == wmax);
    const int owner = __ffsll(own) - 1;               // lowest lane: first-max
    int idx = __shfl(bn, owner);
    idx = __builtin_amdgcn_readfirstlane(idx);
    idxs[k] = idx;

    // ---- gram column for future corr updates (vector, L2-resident)
    if (k < NSPARSE - 1) {
      const float4 g0 = *reinterpret_cast<const float4*>(
          &gram[(size_t)idx * NATOMS + 8 * lane]);
      const float4 g1 = *reinterpret_cast<const float4*>(
          &gram[(size_t)idx * NATOMS + 8 * lane + 4]);
      gc[k][0] = g0.x; gc[k][1] = g0.y; gc[k][2] = g0.z; gc[k][3] = g0.w;
      gc[k][4] = g1.x; gc[k][5] = g1.y; gc[k][6] = g1.z; gc[k][7] = g1.w;
    }

    // ---- rhs: one uniform LDS read (broadcast)
    rhsf[k] = dtxT[wave][idx];

    // ---- Gram row k entries: uniform addresses -> scalar loads
    float arowf[NSPARSE];
#pragma unroll
    for (int j = 0; j < k; ++j)
      arowf[j] = gram[(size_t)idx * NATOMS + idxs[j]];
    const float gdiag = gram[(size_t)idx * NATOMS + idx];

    // ---- incremental Cholesky row k of (G_active + eps*I), rsqrt-based
    double ss = (double)gdiag + DEPS;
#pragma unroll
    for (int j = 0; j < k; ++j) {
      double w = (double)arowf[j];
#pragma unroll
      for (int tt = 0; tt < j; ++tt) w -= L[k][tt] * L[j][tt];
      w *= inv_d[j];
      L[k][j] = w;
      ss -= w * w;
    }
    const double inv = rsqrt(ss);
    L[k][k]  = ss * inv;                    // = sqrt(ss)
    inv_d[k] = inv;

    // ---- forward substitution: only y[k] is new (y[0..k-1] unchanged)
    {
      double s2 = (double)rhsf[k];
#pragma unroll
      for (int j = 0; j < k; ++j) s2 -= L[k][j] * y[j];
      y[k] = s2 * inv;
    }
    // ---- backward substitution (full, sol changes every round)
#pragma unroll
    for (int i = k; i >= 0; --i) {
      double s2 = y[i];
#pragma unroll
      for (int j = i + 1; j <= k; ++j) s2 -= L[j][i] * sol[j];
      sol[i] = s2 * inv_d[i];
    }
  }

  // ---- epilogue: scatter the 5 coefficients (out pre-zeroed)
  if (lane == 0) {
#pragma unroll
    for (int s = 0; s < NSPARSE; ++s)
      out[(size_t)idxs[s] * BATCH + cglob] = (float)sol[s];
  }
}

// ---------------------------------------------------------------------------
extern "C" void kernel_launch(void* const* d_in, const int* in_sizes, int n_in,
                              void* d_out, int out_size, void* d_ws,
                              size_t ws_size, hipStream_t stream) {
  (void)in_sizes; (void)n_in; (void)out_size; (void)ws_size;
  const float* X = (const float*)d_in[0];   // (64, 65536)
  const float* D = (const float*)d_in[1];   // (64, 512)
  float* out = (float*)d_out;               // (512, 65536)
  float* gram = (float*)d_ws;               // 1 MB scratch

  ksvd_prep<<<(NATOMS * NATOMS) / 256, 256, 0, stream>>>(D, gram);
  hipMemsetAsync(out, 0, (size_t)NATOMS * BATCH * sizeof(float), stream);
  ksvd_main<<<BATCH / BT, 256, 0, stream>>>(X, D, gram, out);
}